// Round 4
// baseline (1229.715 us; speedup 1.0000x reference)
//
#include <hip/hip_runtime.h>

#define B_ROWS 8192
#define DIM_   4096
#define HID_   256
#define NH_    16
#define SEQ_   2048
#define BK     64

typedef __attribute__((ext_vector_type(8))) short short8;
typedef __attribute__((ext_vector_type(4))) float float4v;
typedef unsigned short ushort_t;

typedef const void __attribute__((address_space(1)))* as1_cvp;
typedef void __attribute__((address_space(3)))* as3_vp;

__device__ __forceinline__ void gload_lds16(const void* g, void* l) {
  __builtin_amdgcn_global_load_lds((as1_cvp)g, (as3_vp)l, 16, 0, 0);
}

// RNE float -> bf16 (finite inputs only)
__device__ __forceinline__ ushort_t f2bf(float f) {
  union { float f; unsigned u; } a;
  a.f = f;
  unsigned r = a.u + 0x7FFFu + ((a.u >> 16) & 1u);
  return (ushort_t)(r >> 16);
}

// ---------------- merged prep kernel --------------------------------------
// blocks [0,8192):      cvt x (fp32->bf16), 4096 elems/block
// blocks [8192,12288):  tr_wproj (16,4096,256)->(16,256,4096) bf16, 64x64 tiles
// blocks [12288,16384): tr_wout  (4096,4096)->transposed bf16, 64x64 tiles
__global__ __launch_bounds__(256)
void uber_prep(const float* __restrict__ x, ushort_t* __restrict__ xbf,
               const float* __restrict__ W_proj, ushort_t* __restrict__ Bt1,
               const float* __restrict__ W_out, ushort_t* __restrict__ Bt2) {
  __shared__ float tile[64][65];
  const int bid = blockIdx.x;
  const int tid = threadIdx.x;
  if (bid < 8192) {
    const long base = (long)bid * 4096 + tid * 4;
    #pragma unroll
    for (int j = 0; j < 4; ++j) {
      const long i = base + j * 1024;
      const float4v v = *(const float4v*)(x + i);
      ushort4 o;
      o.x = f2bf(v.x); o.y = f2bf(v.y); o.z = f2bf(v.z); o.w = f2bf(v.w);
      *(ushort4*)(xbf + i) = o;
    }
    return;
  }
  const float* src;
  ushort_t* dst;
  int M0, N0, ncols;
  if (bid < 12288) {
    const int b2 = bid - 8192;
    const int h = b2 >> 8;
    const int t = b2 & 255;
    M0 = (t & 63) * 64;          // over DIM
    N0 = (t >> 6) * 64;          // over HID
    ncols = HID_;
    src = W_proj + (long)h * DIM_ * HID_;
    dst = Bt1 + (long)h * HID_ * DIM_;
  } else {
    const int t = bid - 12288;
    M0 = (t & 63) * 64;
    N0 = (t >> 6) * 64;
    ncols = DIM_;
    src = W_out;
    dst = Bt2;
  }
  #pragma unroll
  for (int j = 0; j < 4; ++j) {
    const int row = (tid >> 4) + j * 16;
    const int c = (tid & 15) * 4;
    const float4v v = *(const float4v*)(src + (long)(M0 + row) * ncols + N0 + c);
    tile[row][c] = v.x; tile[row][c + 1] = v.y;
    tile[row][c + 2] = v.z; tile[row][c + 3] = v.w;
  }
  __syncthreads();
  #pragma unroll
  for (int j = 0; j < 4; ++j) {
    const int orow = (tid >> 4) + j * 16;   // over output rows (N dim of src)
    const int oc = (tid & 15) * 4;          // over output cols (M dim of src)
    ushort4 o;
    o.x = f2bf(tile[oc][orow]);     o.y = f2bf(tile[oc + 1][orow]);
    o.z = f2bf(tile[oc + 2][orow]); o.w = f2bf(tile[oc + 3][orow]);
    *(ushort4*)(dst + (long)(N0 + orow) * DIM_ + M0 + oc) = o;
  }
}

// -------- bf16 MFMA GEMM, C = A(MxK) * Bt(NxK)^T, M=8192, N=K=4096 ------------
// BK=64, XOR-swizzled LDS (zero bank conflicts), supertile dispatch swizzle
// (8 m-blocks x full n per supertile) for LLC locality.
// EPI 0 (scatter, R2-style): hid = w[h]*(acc+b_proj) + cc[h]*caches + b[h] -> bf16
// EPI 1 (scatter):           out = acc + b_out -> fp32
// Streaming epilogue traffic uses nontemporal ld/st to keep A/B in LLC.
template <int EPI>
__launch_bounds__(256)
__global__ void gemm_bt(const ushort_t* __restrict__ A, const ushort_t* __restrict__ Bt,
                        const float* __restrict__ b_proj, const float* __restrict__ caches,
                        const float* __restrict__ w_mix, const float* __restrict__ b_mix,
                        const float* __restrict__ decay, const int* __restrict__ index,
                        const float* __restrict__ b_out,
                        ushort_t* __restrict__ hid_out, float* __restrict__ f_out) {
  __shared__ __attribute__((aligned(16))) ushort_t As[128 * BK];
  __shared__ __attribute__((aligned(16))) ushort_t Bs[128 * BK];
  const int tid = threadIdx.x;
  const int lane = tid & 63;
  const int wave = tid >> 6;
  // supertile swizzle: dispatch order x-fastest; 256 blocks = 8 m x 32 n
  const int lin = blockIdx.x + blockIdx.y * 32;
  const int mb = (lin >> 8) * 8 + (lin & 7);
  const int nb = (lin & 255) >> 3;
  const int m0 = mb * 128;
  const int n0 = nb * 128;
  const int wm = (wave >> 1) * 64;  // 2x2 waves, each 64x64
  const int wn = (wave & 1) * 64;
  const int r16 = lane & 15;
  const int quad = lane >> 4;

  float4v acc[4][4];
  #pragma unroll
  for (int i = 0; i < 4; ++i)
    #pragma unroll
    for (int j = 0; j < 4; ++j)
      acc[i][j] = (float4v){0.f, 0.f, 0.f, 0.f};

  const ushort_t* Abase = A + (long)m0 * DIM_;
  const ushort_t* Bbase = Bt + (long)n0 * DIM_;

  for (int kt = 0; kt < DIM_; kt += BK) {
    // stage 128xBK A and B tiles; XOR swizzle keeps frag reads conflict-free
    // while staging stays lane-contiguous (dest = wave base + lane*16).
    #pragma unroll
    for (int i = 0; i < 4; ++i) {
      const int c = tid + i * 256;
      const int row = c >> 3;
      const int kc = (c & 7) ^ (row & 7);
      gload_lds16(Abase + (long)row * DIM_ + kt + kc * 8, (void*)(As + c * 8));
      gload_lds16(Bbase + (long)row * DIM_ + kt + kc * 8, (void*)(Bs + c * 8));
    }
    __syncthreads();

    #pragma unroll
    for (int ks = 0; ks < BK / 32; ++ks) {
      short8 a_frag[4], b_frag[4];
      const int slot = (ks * 4 + quad) ^ (r16 & 7);
      #pragma unroll
      for (int mi = 0; mi < 4; ++mi)
        a_frag[mi] = *(const short8*)(As + (wm + mi * 16 + r16) * BK + slot * 8);
      #pragma unroll
      for (int ni = 0; ni < 4; ++ni)
        b_frag[ni] = *(const short8*)(Bs + (wn + ni * 16 + r16) * BK + slot * 8);
      #pragma unroll
      for (int mi = 0; mi < 4; ++mi)
        #pragma unroll
        for (int ni = 0; ni < 4; ++ni)
          acc[mi][ni] = __builtin_amdgcn_mfma_f32_16x16x32_bf16(a_frag[mi], b_frag[ni], acc[mi][ni], 0, 0, 0);
    }
    __syncthreads();
  }

  // Epilogue. C/D layout: col = lane&15, row = (lane>>4)*4 + reg  [m89/m91]
  if (EPI == 0) {
    const int h = n0 >> 8;           // whole 128-col block lies in one head
    const int idx0 = *index;
    const float wch = w_mix[h * SEQ_ + idx0];
    const float bch = b_mix[h * SEQ_ + idx0];
    float d = fminf(fmaxf(decay[h], 0.9f), 1.0f);
    d = powf(d, 0.25f);              // 1/DECAY_CONSTANT, DECAY_CONSTANT = 4
    const float cch = (h < NH_ / 2) ? (wch * d) : d;
    const float* cbase = caches + (long)h * B_ROWS * HID_;
    #pragma unroll
    for (int ni = 0; ni < 4; ++ni) {
      const int col = n0 + wn + ni * 16 + r16;
      const int kk = col & 255;
      const float bp = b_proj[col];
      #pragma unroll
      for (int mi = 0; mi < 4; ++mi) {
        #pragma unroll
        for (int r = 0; r < 4; ++r) {
          const long row = m0 + wm + mi * 16 + quad * 4 + r;
          const float cv = __builtin_nontemporal_load(cbase + row * HID_ + kk);
          const float v = wch * (acc[mi][ni][r] + bp) + cch * cv + bch;
          __builtin_nontemporal_store(f2bf(v), hid_out + row * DIM_ + col);
        }
      }
    }
  } else {
    #pragma unroll
    for (int ni = 0; ni < 4; ++ni) {
      const int col = n0 + wn + ni * 16 + r16;
      const float bo = b_out[col];
      #pragma unroll
      for (int mi = 0; mi < 4; ++mi) {
        #pragma unroll
        for (int r = 0; r < 4; ++r) {
          const long row = m0 + wm + mi * 16 + quad * 4 + r;
          __builtin_nontemporal_store(acc[mi][ni][r] + bo, f_out + row * DIM_ + col);
        }
      }
    }
  }
}

extern "C" void kernel_launch(void* const* d_in, const int* in_sizes, int n_in,
                              void* d_out, int out_size, void* d_ws, size_t ws_size,
                              hipStream_t stream) {
  const float* x       = (const float*)d_in[0];
  const int*   index   = (const int*)d_in[1];
  const float* W_proj  = (const float*)d_in[2];
  const float* b_proj  = (const float*)d_in[3];
  const float* W_out   = (const float*)d_in[4];
  const float* b_out   = (const float*)d_in[5];
  const float* w_mix   = (const float*)d_in[6];
  const float* b_mix   = (const float*)d_in[7];
  const float* decay   = (const float*)d_in[8];
  const float* caches  = (const float*)d_in[9];
  float* out = (float*)d_out;

  char* ws = (char*)d_ws;
  // layout: xbf 64MB | Bt1 32MB | Bt2 32MB | hid 64MB  = 192MB
  ushort_t* xbf = (ushort_t*)(ws);
  ushort_t* Bt1 = (ushort_t*)(ws + 67108864L);
  ushort_t* Bt2 = (ushort_t*)(ws + 100663296L);
  ushort_t* hid = (ushort_t*)(ws + 134217728L);

  hipLaunchKernelGGL(uber_prep, dim3(16384), dim3(256), 0, stream,
                     x, xbf, W_proj, Bt1, W_out, Bt2);
  hipLaunchKernelGGL((gemm_bt<0>), dim3(DIM_ / 128, B_ROWS / 128), dim3(256), 0, stream,
                     xbf, Bt1, b_proj, caches, w_mix, b_mix, decay, index, b_out, hid, out);
  hipLaunchKernelGGL((gemm_bt<1>), dim3(DIM_ / 128, B_ROWS / 128), dim3(256), 0, stream,
                     hid, Bt2, b_proj, caches, w_mix, b_mix, decay, index, b_out, hid, out);
}